// Round 15
// baseline (9192.346 us; speedup 1.0000x reference)
//
#include <hip/hip_runtime.h>
#include <cstdint>
#include <cstddef>

// ---------------- types / helpers ----------------
typedef __attribute__((ext_vector_type(8))) short bf16x8;   // 8 bf16 in 4 VGPRs
typedef __attribute__((ext_vector_type(4))) float f32x4;
typedef __attribute__((ext_vector_type(4))) float float4v;
typedef __attribute__((ext_vector_type(4))) unsigned int u32x4;
typedef __attribute__((ext_vector_type(4))) unsigned short ushort4v;
typedef unsigned short u16;
typedef unsigned int u32;

#define DEVFN static __device__ __forceinline__

DEVFN u16 f2bf(float f) {               // fp32 -> bf16 round-to-nearest-even
  u32 u = __float_as_uint(f);
  return (u16)((u + 0x7fffu + ((u >> 16) & 1u)) >> 16);
}
DEVFN float bf2f(u16 h) { return __uint_as_float(((u32)h) << 16); }
DEVFN float sigmf(float x) { return 1.f / (1.f + __expf(-x)); }
DEVFN float tanhf_fast(float x) {
  float e = __expf(-2.f * fabsf(x));
  float t = (1.f - e) / (1.f + e);
  return x >= 0.f ? t : -t;
}

// dims: L=8 N=64 T=128 D=1024 H=1024 ; TL = 1024 steps ; 3H = 3072
// ws: [0,4096) packed arrival cells (4 grp x 64 u32) — HINT only, tags are truth
//     [4096,+512KB) TAGGED h double buffer u32[2][64][1024]: (tag<<16)|bf16
//     then W_hh bf16 (6291456), gi bf16 (65536x3072).  W_ih used as fp32 directly.
static constexpr size_t WS_BAR  = 0;
static constexpr size_t WS_HBUF = 4096;
static constexpr size_t WS_WHH  = WS_HBUF + 524288;
static constexpr size_t WS_GI   = WS_WHH + 6291456;
static constexpr size_t WS_END  = WS_GI + (size_t)65536 * 3072 * 2;  // ~390.5 MiB < r9's proven 396.3
// ---------------- fp32 -> bf16 convert ----------------
__global__ void cvt4_kernel(const float* __restrict__ src, u16* __restrict__ dst, int n4) {
  int i = blockIdx.x * blockDim.x + threadIdx.x;
  if (i >= n4) return;
  float4v v = ((const float4v*)src)[i];
  ushort4v o;
  o[0] = f2bf(v[0]); o[1] = f2bf(v[1]); o[2] = f2bf(v[2]); o[3] = f2bf(v[3]);
  ((ushort4v*)dst)[i] = o;
}

// h0 -> tagged buf0: tag 0 in high 16 bits
__global__ void h0_init_kernel(const float* __restrict__ h0, u32* __restrict__ hbuf) {
  int n = blockIdx.x;
  const float* src = h0 + (size_t)n * 1024;
  u32* dst = hbuf + (size_t)n * 1024;
  for (int i = threadIdx.x; i < 1024; i += 256) dst[i] = (u32)f2bf(src[i]);
}

// ---------------- phase A: gi = xs @ W_ih^T (bf16 out), W_ih read as fp32 ----------------
__launch_bounds__(256, 2)
__global__ void gemm_gi_kernel(const float* __restrict__ x, const float* __restrict__ wihf,
                               u16* __restrict__ gi) {
  const int tid = threadIdx.x;
  const int lane = tid & 63;
  const int wv = tid >> 6;
  const int bid = blockIdx.x;
  const int gt = bid % 24;
  const int rt = bid / 24;

  __shared__ __align__(16) u16 Ash[128 * 32];
  __shared__ __align__(16) u16 Bsh[128 * 32];

  const int ra = tid >> 1;
  const int ch = (tid & 1) * 16;
  const int r  = rt * 128 + ra;
  const int tp = r >> 6, n = r & 63;
  const int ll = tp & 7, tt = tp >> 3;
  const float* arow = x + ((size_t)((ll * 64 + n) * 128 + tt)) * 1024 + ch;
  const float* browf = wihf + ((size_t)(gt * 128 + ra)) * 1024 + ch;
  const int wbyte0 = ra * 64 + ch * 2;
  const int wswz   = (ra & 7) << 4;

  const int rw = (wv >> 1) * 64;
  const int cw = (wv & 1) * 64;
  const int kb = (lane >> 4) * 16;

  f32x4 acc[4][4];
#pragma unroll
  for (int i = 0; i < 4; ++i)
#pragma unroll
    for (int j = 0; j < 4; ++j) acc[i][j] = (f32x4){0.f, 0.f, 0.f, 0.f};

  for (int kt = 0; kt < 32; ++kt) {
    float4v a0 = *(const float4v*)(arow + kt * 32 + 0);
    float4v a1 = *(const float4v*)(arow + kt * 32 + 4);
    float4v a2 = *(const float4v*)(arow + kt * 32 + 8);
    float4v a3 = *(const float4v*)(arow + kt * 32 + 12);
    float4v b0 = *(const float4v*)(browf + kt * 32 + 0);
    float4v b1 = *(const float4v*)(browf + kt * 32 + 4);
    float4v b2 = *(const float4v*)(browf + kt * 32 + 8);
    float4v b3 = *(const float4v*)(browf + kt * 32 + 12);
    union { u16 u[8]; bf16x8 v; } p0, p1, q0, q1;
    p0.u[0] = f2bf(a0[0]); p0.u[1] = f2bf(a0[1]); p0.u[2] = f2bf(a0[2]); p0.u[3] = f2bf(a0[3]);
    p0.u[4] = f2bf(a1[0]); p0.u[5] = f2bf(a1[1]); p0.u[6] = f2bf(a1[2]); p0.u[7] = f2bf(a1[3]);
    p1.u[0] = f2bf(a2[0]); p1.u[1] = f2bf(a2[1]); p1.u[2] = f2bf(a2[2]); p1.u[3] = f2bf(a2[3]);
    p1.u[4] = f2bf(a3[0]); p1.u[5] = f2bf(a3[1]); p1.u[6] = f2bf(a3[2]); p1.u[7] = f2bf(a3[3]);
    q0.u[0] = f2bf(b0[0]); q0.u[1] = f2bf(b0[1]); q0.u[2] = f2bf(b0[2]); q0.u[3] = f2bf(b0[3]);
    q0.u[4] = f2bf(b1[0]); q0.u[5] = f2bf(b1[1]); q0.u[6] = f2bf(b1[2]); q0.u[7] = f2bf(b1[3]);
    q1.u[0] = f2bf(b2[0]); q1.u[1] = f2bf(b2[1]); q1.u[2] = f2bf(b2[2]); q1.u[3] = f2bf(b2[3]);
    q1.u[4] = f2bf(b3[0]); q1.u[5] = f2bf(b3[1]); q1.u[6] = f2bf(b3[2]); q1.u[7] = f2bf(b3[3]);
    *(bf16x8*)((char*)Ash + ((wbyte0 +  0) ^ wswz)) = p0.v;
    *(bf16x8*)((char*)Ash + ((wbyte0 + 16) ^ wswz)) = p1.v;
    *(bf16x8*)((char*)Bsh + ((wbyte0 +  0) ^ wswz)) = q0.v;
    *(bf16x8*)((char*)Bsh + ((wbyte0 + 16) ^ wswz)) = q1.v;
    __syncthreads();

    bf16x8 af[4], bfr[4];
#pragma unroll
    for (int mi = 0; mi < 4; ++mi) {
      int row = rw + mi * 16 + (lane & 15);
      af[mi] = *(const bf16x8*)((char*)Ash + ((row * 64 + kb) ^ ((row & 7) << 4)));
    }
#pragma unroll
    for (int nj = 0; nj < 4; ++nj) {
      int row = cw + nj * 16 + (lane & 15);
      bfr[nj] = *(const bf16x8*)((char*)Bsh + ((row * 64 + kb) ^ ((row & 7) << 4)));
    }
#pragma unroll
    for (int mi = 0; mi < 4; ++mi)
#pragma unroll
      for (int nj = 0; nj < 4; ++nj)
        acc[mi][nj] = __builtin_amdgcn_mfma_f32_16x16x32_bf16(af[mi], bfr[nj], acc[mi][nj], 0, 0, 0);
    __syncthreads();
  }

  const size_t rbase = (size_t)rt * 128;
  const int gbase = gt * 128;
#pragma unroll
  for (int mi = 0; mi < 4; ++mi)
#pragma unroll
    for (int nj = 0; nj < 4; ++nj) {
      int col = gbase + cw + nj * 16 + (lane & 15);
#pragma unroll
      for (int rr = 0; rr < 4; ++rr) {
        int row = rw + mi * 16 + (lane >> 4) * 4 + rr;
        gi[(rbase + row) * 3072 + col] = f2bf(acc[mi][nj][rr]);
      }
    }
}

// ---------------- phase B: persistent GRU scan — SELF-VALIDATING TAGGED h ----------------
// r9 geometry (256 wgs = 4 grp x 64 wgs x 16 cols). h stored as (tag<<16)|bf16
// per u32 (atomic). Consumers verify tags ON THE DATA -> correctness is
// timing-independent (no ordering assumption). Packed cells are a fast HINT
// poll only; any arrive-vs-data skew is caught by a cheap tag re-load.
__launch_bounds__(256, 2)
__global__ void gru_scan_kernel(const u16* __restrict__ gi, const u16* __restrict__ whh,
                                const float* __restrict__ b_ih, const float* __restrict__ b_hh,
                                u32* __restrict__ hbuf, u32* __restrict__ bar,
                                float* __restrict__ out) {
  const int tid = threadIdx.x, lane = tid & 63, wv = tid >> 6;
  const int b = blockIdx.x;
  const int grp = b >> 6;          // batch rows grp*16 .. +16
  const int j0 = (b & 63) * 16;    // hidden cols j0 .. j0+16

  __shared__ float part[4 * 3 * 16 * 17];   // [wave][gate][col][row], stride 17
  __shared__ int dead_s;
  if (tid == 0) dead_s = 0;
  __syncthreads();

  // W_hh fragments: wave wv owns K in [wv*256, +256)
  bf16x8 wreg[3][8];
#pragma unroll
  for (int c = 0; c < 3; ++c) {
    const u16* wp = whh + (size_t)(c * 1024 + j0 + (lane & 15)) * 1024
                        + wv * 256 + (lane >> 4) * 8;
#pragma unroll
    for (int kk = 0; kk < 8; ++kk) wreg[c][kk] = *(const bf16x8*)(wp + kk * 32);
  }

  const int erow = tid >> 4, ej = tid & 15;
  const int en = grp * 16 + erow;
  const int gcol = j0 + ej;
  const float bihr = b_ih[gcol], bihz = b_ih[1024 + gcol], bihn = b_ih[2048 + gcol];
  const float bhhr = b_hh[gcol], bhhz = b_hh[1024 + gcol], bhhn = b_hh[2048 + gcol];

  u32* cells  = bar + grp * 64;             // packed hint cells (256B/group)
  u32* mycell = cells + (b & 63);
  const int aoff32 = (grp * 16 + (lane & 15)) * 1024 + wv * 256 + (lane >> 4) * 8;

  // h(0) from tagged buf0 (tag 0; written by h0_init, kernel-boundary released)
  float hcur = bf2f((u16)(hbuf[(size_t)en * 1024 + gcol] & 0xFFFFu));

  for (int s = 0; s < 1024; ++s) {
    // gi loads (read-once, streaming) — issued before any wait
    size_t gib = ((size_t)(s * 64 + en)) * 3072 + gcol;
    float gir = bf2f(__builtin_nontemporal_load(gi + gib));
    float giz = bf2f(__builtin_nontemporal_load(gi + gib + 1024));
    float gin = bf2f(__builtin_nontemporal_load(gi + gib + 2048));

    // ---- HINT poll (packed cells, coalesced): likely-ready, not correctness ----
    if (s > 0) {
      if (wv == 0) {
        const u32 tgt = (u32)s;
        u32 tries = 0; int ok;
        do {
          u32 v = __hip_atomic_load(cells + lane, __ATOMIC_RELAXED, __HIP_MEMORY_SCOPE_AGENT);
          ok = __all((int)(v >= tgt));
        } while (!ok && ++tries < (1u << 20));
        if (!ok && lane == 0) dead_s = 1;
      }
      __syncthreads();                      // also orders part r/w across steps
      if (dead_s) break;
    }

    // ---- tagged h fragments: load + VERIFY TAGS (the real gate) ----
    const u32* hp32 = hbuf + (size_t)(s & 1) * 65536 + aoff32;
    const u32 expect = (u32)s << 16;
    u32x4 q0, q1, q2, q3, q4, q5, q6, q7, q8, q9, qa, qb, qc, qd, qe, qf;
    {
      u32 tries = 0;
      for (;;) {
        asm volatile("global_load_dwordx4 %0, %1, off sc0 sc1"            : "=v"(q0) : "v"(hp32));
        asm volatile("global_load_dwordx4 %0, %1, off offset:16 sc0 sc1"  : "=v"(q1) : "v"(hp32));
        asm volatile("global_load_dwordx4 %0, %1, off offset:128 sc0 sc1" : "=v"(q2) : "v"(hp32));
        asm volatile("global_load_dwordx4 %0, %1, off offset:144 sc0 sc1" : "=v"(q3) : "v"(hp32));
        asm volatile("global_load_dwordx4 %0, %1, off offset:256 sc0 sc1" : "=v"(q4) : "v"(hp32));
        asm volatile("global_load_dwordx4 %0, %1, off offset:272 sc0 sc1" : "=v"(q5) : "v"(hp32));
        asm volatile("global_load_dwordx4 %0, %1, off offset:384 sc0 sc1" : "=v"(q6) : "v"(hp32));
        asm volatile("global_load_dwordx4 %0, %1, off offset:400 sc0 sc1" : "=v"(q7) : "v"(hp32));
        asm volatile("global_load_dwordx4 %0, %1, off offset:512 sc0 sc1" : "=v"(q8) : "v"(hp32));
        asm volatile("global_load_dwordx4 %0, %1, off offset:528 sc0 sc1" : "=v"(q9) : "v"(hp32));
        asm volatile("global_load_dwordx4 %0, %1, off offset:640 sc0 sc1" : "=v"(qa) : "v"(hp32));
        asm volatile("global_load_dwordx4 %0, %1, off offset:656 sc0 sc1" : "=v"(qb) : "v"(hp32));
        asm volatile("global_load_dwordx4 %0, %1, off offset:768 sc0 sc1" : "=v"(qc) : "v"(hp32));
        asm volatile("global_load_dwordx4 %0, %1, off offset:784 sc0 sc1" : "=v"(qd) : "v"(hp32));
        asm volatile("global_load_dwordx4 %0, %1, off offset:896 sc0 sc1" : "=v"(qe) : "v"(hp32));
        asm volatile("global_load_dwordx4 %0, %1, off offset:912 sc0 sc1" : "=v"(qf) : "v"(hp32));
        asm volatile("s_waitcnt vmcnt(0)" ::: "memory");
        u32 bad = (q0[0]^expect)|(q0[1]^expect)|(q0[2]^expect)|(q0[3]^expect)
                | (q1[0]^expect)|(q1[1]^expect)|(q1[2]^expect)|(q1[3]^expect)
                | (q2[0]^expect)|(q2[1]^expect)|(q2[2]^expect)|(q2[3]^expect)
                | (q3[0]^expect)|(q3[1]^expect)|(q3[2]^expect)|(q3[3]^expect)
                | (q4[0]^expect)|(q4[1]^expect)|(q4[2]^expect)|(q4[3]^expect)
                | (q5[0]^expect)|(q5[1]^expect)|(q5[2]^expect)|(q5[3]^expect)
                | (q6[0]^expect)|(q6[1]^expect)|(q6[2]^expect)|(q6[3]^expect)
                | (q7[0]^expect)|(q7[1]^expect)|(q7[2]^expect)|(q7[3]^expect)
                | (q8[0]^expect)|(q8[1]^expect)|(q8[2]^expect)|(q8[3]^expect)
                | (q9[0]^expect)|(q9[1]^expect)|(q9[2]^expect)|(q9[3]^expect)
                | (qa[0]^expect)|(qa[1]^expect)|(qa[2]^expect)|(qa[3]^expect)
                | (qb[0]^expect)|(qb[1]^expect)|(qb[2]^expect)|(qb[3]^expect)
                | (qc[0]^expect)|(qc[1]^expect)|(qc[2]^expect)|(qc[3]^expect)
                | (qd[0]^expect)|(qd[1]^expect)|(qd[2]^expect)|(qd[3]^expect)
                | (qe[0]^expect)|(qe[1]^expect)|(qe[2]^expect)|(qe[3]^expect)
                | (qf[0]^expect)|(qf[1]^expect)|(qf[2]^expect)|(qf[3]^expect);
        bad &= 0xFFFF0000u;
        if (__all((int)(bad == 0u))) break;
        if (++tries >= (1u << 18)) { if (lane == 0) dead_s = 1; break; }
        __builtin_amdgcn_s_sleep(1);
      }
    }
    __builtin_amdgcn_sched_barrier(0);      // rule #18: MFMA stays below the waitcnt

    // unpack low halves -> bf16 fragments
    union U { u16 u[8]; bf16x8 v; };
#define UNPK(D, QA, QB) { U t_; t_.u[0]=(u16)QA[0]; t_.u[1]=(u16)QA[1]; t_.u[2]=(u16)QA[2]; t_.u[3]=(u16)QA[3]; \
                          t_.u[4]=(u16)QB[0]; t_.u[5]=(u16)QB[1]; t_.u[6]=(u16)QB[2]; t_.u[7]=(u16)QB[3]; D = t_.v; }
    bf16x8 af0, af1, af2, af3, af4, af5, af6, af7;
    UNPK(af0, q0, q1) UNPK(af1, q2, q3) UNPK(af2, q4, q5) UNPK(af3, q6, q7)
    UNPK(af4, q8, q9) UNPK(af5, qa, qb) UNPK(af6, qc, qd) UNPK(af7, qe, qf)
#undef UNPK

    f32x4 acc[3];
    acc[0] = (f32x4){0.f, 0.f, 0.f, 0.f}; acc[1] = acc[0]; acc[2] = acc[0];
#pragma unroll
    for (int c = 0; c < 3; ++c) {
      acc[c] = __builtin_amdgcn_mfma_f32_16x16x32_bf16(af0, wreg[c][0], acc[c], 0, 0, 0);
      acc[c] = __builtin_amdgcn_mfma_f32_16x16x32_bf16(af1, wreg[c][1], acc[c], 0, 0, 0);
      acc[c] = __builtin_amdgcn_mfma_f32_16x16x32_bf16(af2, wreg[c][2], acc[c], 0, 0, 0);
      acc[c] = __builtin_amdgcn_mfma_f32_16x16x32_bf16(af3, wreg[c][3], acc[c], 0, 0, 0);
      acc[c] = __builtin_amdgcn_mfma_f32_16x16x32_bf16(af4, wreg[c][4], acc[c], 0, 0, 0);
      acc[c] = __builtin_amdgcn_mfma_f32_16x16x32_bf16(af5, wreg[c][5], acc[c], 0, 0, 0);
      acc[c] = __builtin_amdgcn_mfma_f32_16x16x32_bf16(af6, wreg[c][6], acc[c], 0, 0, 0);
      acc[c] = __builtin_amdgcn_mfma_f32_16x16x32_bf16(af7, wreg[c][7], acc[c], 0, 0, 0);
    }
#pragma unroll
    for (int c = 0; c < 3; ++c) {
      float* pp = &part[((wv * 3 + c) * 16 + (lane & 15)) * 17 + (lane >> 4) * 4];
      pp[0] = acc[c][0]; pp[1] = acc[c][1]; pp[2] = acc[c][2]; pp[3] = acc[c][3];
    }
    __syncthreads();

    float ghr = 0.f, ghz = 0.f, ghn = 0.f;
#pragma unroll
    for (int ww = 0; ww < 4; ++ww) {
      ghr += part[((ww * 3 + 0) * 16 + ej) * 17 + erow];
      ghz += part[((ww * 3 + 1) * 16 + ej) * 17 + erow];
      ghn += part[((ww * 3 + 2) * 16 + ej) * 17 + erow];
    }
    float rg = sigmf(gir + bihr + ghr + bhhr);
    float zg = sigmf(giz + bihz + ghz + bhhz);
    float ng = tanhf_fast(gin + bihn + rg * (ghn + bhhn));
    float hn = (1.f - zg) * ng + zg * hcur;
    hcur = hn;

    // tagged h broadcast: one atomic u32 per thread, tag = s+1 travels WITH data
    __hip_atomic_store(hbuf + (size_t)((s + 1) & 1) * 65536 + (size_t)en * 1024 + gcol,
                       ((u32)(s + 1) << 16) | (u32)f2bf(hn),
                       __ATOMIC_RELAXED, __HIP_MEMORY_SCOPE_AGENT);

    __syncthreads();                        // block's stores issued (hint accuracy)
    if (tid == 0)
      __hip_atomic_fetch_add(mycell, 1u, __ATOMIC_RELAXED, __HIP_MEMORY_SCOPE_AGENT);

    // out stores post-arrive: HBM acks overlap next step's work
    __builtin_nontemporal_store(hn, &out[(size_t)en * 1048576 + (size_t)s * 1024 + gcol]);
    if (s == 1023) out[(size_t)67108864 + (size_t)en * 1024 + gcol] = hn;
  }
}

// ---------------- launch ----------------
extern "C" void kernel_launch(void* const* d_in, const int* in_sizes, int n_in,
                              void* d_out, int out_size, void* d_ws, size_t ws_size,
                              hipStream_t stream) {
  const float* x     = (const float*)d_in[0];
  const float* h0    = (const float*)d_in[1];
  const float* wih_f = (const float*)d_in[2];
  const float* whh_f = (const float*)d_in[3];
  const float* bih   = (const float*)d_in[4];
  const float* bhh   = (const float*)d_in[5];
  float* out = (float*)d_out;

  if (ws_size < WS_END) return;

  char* ws = (char*)d_ws;
  u32* bar   = (u32*)(ws + WS_BAR);
  u32* hbuf  = (u32*)(ws + WS_HBUF);
  u16* whh_b = (u16*)(ws + WS_WHH);
  u16* gi    = (u16*)(ws + WS_GI);

  hipMemsetAsync(bar, 0, 4096, stream);      // hint cells zeroed every replay
  hipMemsetAsync(hbuf, 0xFF, 524288, stream);// stale tags -> 0xFFFF (≠ any 0..1024)

  cvt4_kernel<<<3072, 256, 0, stream>>>(whh_f, whh_b, 786432);
  h0_init_kernel<<<64, 256, 0, stream>>>(h0, hbuf);

  gemm_gi_kernel<<<12288, 256, 0, stream>>>(x, wih_f, gi);

  gru_scan_kernel<<<256, 256, 0, stream>>>(gi, whh_b, bih, bhh, hbuf, bar, out);
}

// Round 16
// 4568.966 us; speedup vs baseline: 2.0119x; 2.0119x over previous
//
#include <hip/hip_runtime.h>
#include <cstdint>
#include <cstddef>

// ---------------- types / helpers ----------------
typedef __attribute__((ext_vector_type(8))) short bf16x8;   // 8 bf16 in 4 VGPRs
typedef __attribute__((ext_vector_type(4))) float f32x4;
typedef __attribute__((ext_vector_type(4))) float float4v;
typedef __attribute__((ext_vector_type(4))) unsigned short ushort4v;
typedef unsigned short u16;
typedef unsigned int u32;

#define DEVFN static __device__ __forceinline__

DEVFN u16 f2bf(float f) {               // fp32 -> bf16 round-to-nearest-even
  u32 u = __float_as_uint(f);
  return (u16)((u + 0x7fffu + ((u >> 16) & 1u)) >> 16);
}
DEVFN float bf2f(u16 h) { return __uint_as_float(((u32)h) << 16); }
DEVFN float sigmf(float x) { return 1.f / (1.f + __expf(-x)); }
DEVFN float tanhf_fast(float x) {
  float e = __expf(-2.f * fabsf(x));
  float t = (1.f - e) / (1.f + e);
  return x >= 0.f ? t : -t;
}

// dims: L=8 N=64 T=128 D=1024 H=1024 ; TL = 1024 steps ; 3H = 3072
// ws: [0,32768) arrival cells: 4 groups x 64 cells x 128B (one line per block)
//     [32768,+256KB) h bf16 double buffer [2][64][1024]
static constexpr size_t WS_BAR  = 0;
static constexpr size_t WS_HBUF = 32768;
static constexpr size_t WS_WIH  = WS_HBUF + 262144;
static constexpr size_t WS_WHH  = WS_WIH + 6291456;
static constexpr size_t WS_GI   = WS_WHH + 6291456;
static constexpr size_t WS_END  = WS_GI + (size_t)65536 * 3072 * 2;  // ~396 MiB

// ---------------- fp32 -> bf16 convert ----------------
__global__ void cvt4_kernel(const float* __restrict__ src, u16* __restrict__ dst, int n4) {
  int i = blockIdx.x * blockDim.x + threadIdx.x;
  if (i >= n4) return;
  float4v v = ((const float4v*)src)[i];
  ushort4v o;
  o[0] = f2bf(v[0]); o[1] = f2bf(v[1]); o[2] = f2bf(v[2]); o[3] = f2bf(v[3]);
  ((ushort4v*)dst)[i] = o;
}

// ---------------- phase A: gi = xs @ W_ih^T (bf16 out) — proven ----------------
__launch_bounds__(256, 2)
__global__ void gemm_gi_kernel(const float* __restrict__ x, const u16* __restrict__ wih,
                               u16* __restrict__ gi) {
  const int tid = threadIdx.x;
  const int lane = tid & 63;
  const int wv = tid >> 6;
  const int bid = blockIdx.x;
  const int gt = bid % 24;
  const int rt = bid / 24;

  __shared__ __align__(16) u16 Ash[128 * 32];
  __shared__ __align__(16) u16 Bsh[128 * 32];

  const int ra = tid >> 1;
  const int ch = (tid & 1) * 16;
  const int r  = rt * 128 + ra;
  const int tp = r >> 6, n = r & 63;
  const int ll = tp & 7, tt = tp >> 3;
  const float* arow = x + ((size_t)((ll * 64 + n) * 128 + tt)) * 1024 + ch;
  const u16*   brow = wih + ((size_t)(gt * 128 + ra)) * 1024 + ch;
  const int wbyte0 = ra * 64 + ch * 2;
  const int wswz   = (ra & 7) << 4;

  const int rw = (wv >> 1) * 64;
  const int cw = (wv & 1) * 64;
  const int kb = (lane >> 4) * 16;

  f32x4 acc[4][4];
#pragma unroll
  for (int i = 0; i < 4; ++i)
#pragma unroll
    for (int j = 0; j < 4; ++j) acc[i][j] = (f32x4){0.f, 0.f, 0.f, 0.f};

  for (int kt = 0; kt < 32; ++kt) {
    float4v a0 = *(const float4v*)(arow + kt * 32 + 0);
    float4v a1 = *(const float4v*)(arow + kt * 32 + 4);
    float4v a2 = *(const float4v*)(arow + kt * 32 + 8);
    float4v a3 = *(const float4v*)(arow + kt * 32 + 12);
    bf16x8 b0 = *(const bf16x8*)(brow + kt * 32 + 0);
    bf16x8 b1 = *(const bf16x8*)(brow + kt * 32 + 8);
    union { u16 u[8]; bf16x8 v; } p0, p1;
    p0.u[0] = f2bf(a0[0]); p0.u[1] = f2bf(a0[1]); p0.u[2] = f2bf(a0[2]); p0.u[3] = f2bf(a0[3]);
    p0.u[4] = f2bf(a1[0]); p0.u[5] = f2bf(a1[1]); p0.u[6] = f2bf(a1[2]); p0.u[7] = f2bf(a1[3]);
    p1.u[0] = f2bf(a2[0]); p1.u[1] = f2bf(a2[1]); p1.u[2] = f2bf(a2[2]); p1.u[3] = f2bf(a2[3]);
    p1.u[4] = f2bf(a3[0]); p1.u[5] = f2bf(a3[1]); p1.u[6] = f2bf(a3[2]); p1.u[7] = f2bf(a3[3]);
    *(bf16x8*)((char*)Ash + ((wbyte0 +  0) ^ wswz)) = p0.v;
    *(bf16x8*)((char*)Ash + ((wbyte0 + 16) ^ wswz)) = p1.v;
    *(bf16x8*)((char*)Bsh + ((wbyte0 +  0) ^ wswz)) = b0;
    *(bf16x8*)((char*)Bsh + ((wbyte0 + 16) ^ wswz)) = b1;
    __syncthreads();

    bf16x8 af[4], bfr[4];
#pragma unroll
    for (int mi = 0; mi < 4; ++mi) {
      int row = rw + mi * 16 + (lane & 15);
      af[mi] = *(const bf16x8*)((char*)Ash + ((row * 64 + kb) ^ ((row & 7) << 4)));
    }
#pragma unroll
    for (int nj = 0; nj < 4; ++nj) {
      int row = cw + nj * 16 + (lane & 15);
      bfr[nj] = *(const bf16x8*)((char*)Bsh + ((row * 64 + kb) ^ ((row & 7) << 4)));
    }
#pragma unroll
    for (int mi = 0; mi < 4; ++mi)
#pragma unroll
      for (int nj = 0; nj < 4; ++nj)
        acc[mi][nj] = __builtin_amdgcn_mfma_f32_16x16x32_bf16(af[mi], bfr[nj], acc[mi][nj], 0, 0, 0);
    __syncthreads();
  }

  const size_t rbase = (size_t)rt * 128;
  const int gbase = gt * 128;
#pragma unroll
  for (int mi = 0; mi < 4; ++mi)
#pragma unroll
    for (int nj = 0; nj < 4; ++nj) {
      int col = gbase + cw + nj * 16 + (lane & 15);
#pragma unroll
      for (int rr = 0; rr < 4; ++rr) {
        int row = rw + mi * 16 + (lane >> 4) * 4 + rr;
        gi[(rbase + row) * 3072 + col] = f2bf(acc[mi][nj][rr]);
      }
    }
}

// ---------------- phase B: persistent GRU scan (r9 — session optimum) ----------------
// 256 wgs = 4 groups (16 rows) x 64 wgs (16 cols). W_hh in VGPRs (96/lane).
// Fence-free: per-block-cell RMW arrive (line-strided), agent atomic poll,
// agent relaxed atomic h stores, sc0+sc1 16B L3-direct h loads. The slow
// line-strided poll is REQUIRED: it provides the latency margin that covers
// the store-ack!=L3-visibility window (packed/fast variants race — r6/r11).
__launch_bounds__(256, 2)
__global__ void gru_scan_kernel(const u16* __restrict__ gi, const u16* __restrict__ whh,
                                const float* __restrict__ h0,
                                const float* __restrict__ b_ih, const float* __restrict__ b_hh,
                                u16* __restrict__ hbuf, u32* __restrict__ bar,
                                float* __restrict__ out) {
  const int tid = threadIdx.x, lane = tid & 63, wv = tid >> 6;
  const int b = blockIdx.x;
  const int grp = b >> 6;          // batch rows grp*16 .. +16
  const int j0 = (b & 63) * 16;    // hidden cols j0 .. j0+16

  __shared__ float part[4 * 3 * 16 * 17];   // [wave][gate][col][row], stride 17
  __shared__ int dead_s;
  if (tid == 0) dead_s = 0;
  __syncthreads();

  // W_hh fragments: wave wv owns K in [wv*256, +256)
  bf16x8 wreg[3][8];
#pragma unroll
  for (int c = 0; c < 3; ++c) {
    const u16* wp = whh + (size_t)(c * 1024 + j0 + (lane & 15)) * 1024
                        + wv * 256 + (lane >> 4) * 8;
#pragma unroll
    for (int kk = 0; kk < 8; ++kk) wreg[c][kk] = *(const bf16x8*)(wp + kk * 32);
  }

  const int erow = tid >> 4, ej = tid & 15;
  const int en = grp * 16 + erow;
  const int gcol = j0 + ej;
  const float bihr = b_ih[gcol], bihz = b_ih[1024 + gcol], bihn = b_ih[2048 + gcol];
  const float bhhr = b_hh[gcol], bhhz = b_hh[1024 + gcol], bhhn = b_hh[2048 + gcol];
  float hcur = h0[(size_t)en * 1024 + gcol];

  u32* cells  = bar + grp * 2048;           // group stride 8KB; cell stride 128B
  u32* mycell = cells + (b & 63) * 32;
  const int aoff = (grp * 16 + (lane & 15)) * 1024 + wv * 256 + (lane >> 4) * 8;

  for (int s = 0; s < 1024; ++s) {
    const u16* hb  = hbuf + (size_t)(s & 1) * 65536;
    u16*       hbn = hbuf + (size_t)((s + 1) & 1) * 65536;

    // gi loads (read-once, streaming)
    size_t gib = ((size_t)(s * 64 + en)) * 3072 + gcol;
    float gir = bf2f(__builtin_nontemporal_load(gi + gib));
    float giz = bf2f(__builtin_nontemporal_load(gi + gib + 1024));
    float gin = bf2f(__builtin_nontemporal_load(gi + gib + 2048));

    // h fragments: sc0+sc1 16B loads — bypass L1+L2, read L3 directly.
    const u16* hp = hb + aoff;
    bf16x8 af0, af1, af2, af3, af4, af5, af6, af7;
    asm volatile("global_load_dwordx4 %0, %1, off sc0 sc1"            : "=v"(af0) : "v"(hp));
    asm volatile("global_load_dwordx4 %0, %1, off offset:64 sc0 sc1"  : "=v"(af1) : "v"(hp));
    asm volatile("global_load_dwordx4 %0, %1, off offset:128 sc0 sc1" : "=v"(af2) : "v"(hp));
    asm volatile("global_load_dwordx4 %0, %1, off offset:192 sc0 sc1" : "=v"(af3) : "v"(hp));
    asm volatile("global_load_dwordx4 %0, %1, off offset:256 sc0 sc1" : "=v"(af4) : "v"(hp));
    asm volatile("global_load_dwordx4 %0, %1, off offset:320 sc0 sc1" : "=v"(af5) : "v"(hp));
    asm volatile("global_load_dwordx4 %0, %1, off offset:384 sc0 sc1" : "=v"(af6) : "v"(hp));
    asm volatile("global_load_dwordx4 %0, %1, off offset:448 sc0 sc1" : "=v"(af7) : "v"(hp));
    asm volatile("s_waitcnt vmcnt(0)" ::: "memory");
    __builtin_amdgcn_sched_barrier(0);      // rule #18: keep MFMA below the waitcnt

    f32x4 acc[3];
    acc[0] = (f32x4){0.f, 0.f, 0.f, 0.f}; acc[1] = acc[0]; acc[2] = acc[0];
#pragma unroll
    for (int c = 0; c < 3; ++c) {
      acc[c] = __builtin_amdgcn_mfma_f32_16x16x32_bf16(af0, wreg[c][0], acc[c], 0, 0, 0);
      acc[c] = __builtin_amdgcn_mfma_f32_16x16x32_bf16(af1, wreg[c][1], acc[c], 0, 0, 0);
      acc[c] = __builtin_amdgcn_mfma_f32_16x16x32_bf16(af2, wreg[c][2], acc[c], 0, 0, 0);
      acc[c] = __builtin_amdgcn_mfma_f32_16x16x32_bf16(af3, wreg[c][3], acc[c], 0, 0, 0);
      acc[c] = __builtin_amdgcn_mfma_f32_16x16x32_bf16(af4, wreg[c][4], acc[c], 0, 0, 0);
      acc[c] = __builtin_amdgcn_mfma_f32_16x16x32_bf16(af5, wreg[c][5], acc[c], 0, 0, 0);
      acc[c] = __builtin_amdgcn_mfma_f32_16x16x32_bf16(af6, wreg[c][6], acc[c], 0, 0, 0);
      acc[c] = __builtin_amdgcn_mfma_f32_16x16x32_bf16(af7, wreg[c][7], acc[c], 0, 0, 0);
    }
#pragma unroll
    for (int c = 0; c < 3; ++c) {
      float* pp = &part[((wv * 3 + c) * 16 + (lane & 15)) * 17 + (lane >> 4) * 4];
      pp[0] = acc[c][0]; pp[1] = acc[c][1]; pp[2] = acc[c][2]; pp[3] = acc[c][3];
    }
    __syncthreads();

    float ghr = 0.f, ghz = 0.f, ghn = 0.f;
#pragma unroll
    for (int ww = 0; ww < 4; ++ww) {
      ghr += part[((ww * 3 + 0) * 16 + ej) * 17 + erow];
      ghz += part[((ww * 3 + 1) * 16 + ej) * 17 + erow];
      ghn += part[((ww * 3 + 2) * 16 + ej) * 17 + erow];
    }
    float rg = sigmf(gir + bihr + ghr + bhhr);
    float zg = sigmf(giz + bihz + ghz + bhhz);
    float ng = tanhf_fast(gin + bihn + rg * (ghn + bhhn));
    float hn = (1.f - zg) * ng + zg * hcur;
    hcur = hn;

    // h broadcast: packed u32, agent-scope relaxed store (proven write path)
    u32 me = f2bf(hn);
    u32 nb = __shfl_down(me, 1);
    if (!(ej & 1))
      __hip_atomic_store((u32*)&hbn[en * 1024 + gcol], me | (nb << 16),
                         __ATOMIC_RELAXED, __HIP_MEMORY_SCOPE_AGENT);

    // ---- group barrier: per-cell RMW arrive + wave-parallel poll (NO fence) ----
    __syncthreads();                 // drains h stores (vmcnt0)
    if (tid == 0)
      __hip_atomic_fetch_add(mycell, 1u, __ATOMIC_RELAXED, __HIP_MEMORY_SCOPE_AGENT);
    if (wv == 0) {
      const u32 tgt = (u32)(s + 1);
      u32 tries = 0; int ok;
      do {
        u32 v = __hip_atomic_load(cells + lane * 32, __ATOMIC_RELAXED, __HIP_MEMORY_SCOPE_AGENT);
        ok = __all((int)(v >= tgt));
      } while (!ok && ++tries < (1u << 20));
      if (!ok && lane == 0) dead_s = 1;        // bounded-spin escape: fail fast
    }
    __syncthreads();
    if (dead_s) break;

    // out stores post-barrier: HBM acks overlap next step's work
    __builtin_nontemporal_store(hn, &out[(size_t)en * 1048576 + (size_t)s * 1024 + gcol]);
    if (s == 1023) out[(size_t)67108864 + (size_t)en * 1024 + gcol] = hn;
  }
}

// ---------------- launch ----------------
extern "C" void kernel_launch(void* const* d_in, const int* in_sizes, int n_in,
                              void* d_out, int out_size, void* d_ws, size_t ws_size,
                              hipStream_t stream) {
  const float* x     = (const float*)d_in[0];
  const float* h0    = (const float*)d_in[1];
  const float* wih_f = (const float*)d_in[2];
  const float* whh_f = (const float*)d_in[3];
  const float* bih   = (const float*)d_in[4];
  const float* bhh   = (const float*)d_in[5];
  float* out = (float*)d_out;

  if (ws_size < WS_END) return;

  char* ws = (char*)d_ws;
  u32* bar   = (u32*)(ws + WS_BAR);
  u16* hbuf  = (u16*)(ws + WS_HBUF);
  u16* wih_b = (u16*)(ws + WS_WIH);
  u16* whh_b = (u16*)(ws + WS_WHH);
  u16* gi    = (u16*)(ws + WS_GI);

  hipMemsetAsync(bar, 0, 32768, stream);  // all arrival cells zeroed every replay

  cvt4_kernel<<<3072, 256, 0, stream>>>(wih_f, wih_b, 786432);
  cvt4_kernel<<<3072, 256, 0, stream>>>(whh_f, whh_b, 786432);
  cvt4_kernel<<<64,   256, 0, stream>>>(h0, hbuf, 16384);   // h buffer 0 init

  gemm_gi_kernel<<<12288, 256, 0, stream>>>(x, wih_b, gi);

  gru_scan_kernel<<<256, 256, 0, stream>>>(gi, whh_b, h0, bih, bhh, hbuf, bar, out);
}